// Round 12
// baseline (290.771 us; speedup 1.0000x reference)
//
#include <hip/hip_runtime.h>
#include <hip/hip_bf16.h>
#include <math.h>

// TopK router: logits = x @ gate_w^T, softmax, top-2, renormalize.
// M=32768 tokens, K=4096, E=64 experts.
// Outputs (concat, harness reads whole buffer as float32):
//   d_out[0 .. 2M)  : top-2 weights (descending)
//   d_out[2M .. 4M) : top-2 expert indices, stored as float values
//
// R11 = R10 with the gemm_part RACE FIXED: the 4 waves' partial tiles are
// reduced in LDS (Wp[4][2048], router_single's proven pattern) and ONE
// reduced tile per block is written to global scratch. Structure:
//   prep_b      : pack gw -> bf16 hi/lo MFMA fragments (1 MB, L2-hot)
//   gemm_part   : streaming partial GEMM, nkc x 1024 blocks
//   reduce_topk : sum nkc partials + top-3/TAU/fp64-refine epilogue
// Fallback: R8-equivalent single kernel if ws too small.

typedef __attribute__((ext_vector_type(8))) short short8;
typedef __attribute__((ext_vector_type(4))) float f32x4;

#define TAU 1e-4f   // near-tie refine threshold (4-term logit noise ~1e-6)
#define LROW 68     // padded logits stride (floats)

__device__ __forceinline__ void cvt8(const f32x4* v, short8* hi, short8* lo) {
    const float* f = reinterpret_cast<const float*>(v);
#pragma unroll
    for (int j = 0; j < 8; ++j) {
        __hip_bfloat16 h = __float2bfloat16(f[j]);
        float r = f[j] - __bfloat162float(h);
        __hip_bfloat16 l = __float2bfloat16(r);
        (*hi)[j] = (short)*reinterpret_cast<unsigned short*>(&h);
        (*lo)[j] = (short)*reinterpret_cast<unsigned short*>(&l);
    }
}

// Pack gw (64x4096 f32) into MFMA-fragment-ordered bf16 hi/lo arrays:
// entry (nt*8192 + w*64 + ln) holds 8 bf16 of row nt*16+(ln&15),
// k = w*32 + (ln>>4)*8 .. +8.  A wave's 64 lanes read 1KB contiguous.
__global__ void prep_b(const float* __restrict__ gw,
                       short8* __restrict__ bh, short8* __restrict__ bl) {
    const int tid = blockIdx.x * 256 + threadIdx.x;   // 0..32767
    const int ln  = tid & 63;
    const int w   = (tid >> 6) & 127;
    const int nt  = tid >> 13;
    const int row = nt * 16 + (ln & 15);
    const int k   = w * 32 + ((ln >> 4) << 3);
    f32x4 v[2];
    v[0] = *reinterpret_cast<const f32x4*>(gw + (long)row * 4096 + k);
    v[1] = *reinterpret_cast<const f32x4*>(gw + (long)row * 4096 + k + 4);
    short8 h, l;
    cvt8(v, &h, &l);
    bh[tid] = h;
    bl[tid] = l;
}

// One k=32 window (R5/R8-proven): B loads, cvt current A, prefetch next A
// into the same regs, then 32 MFMA (4-term hh+hl+lh+ll).
#define WSTEP(WIDX, PREOFF) do {                                              \
    const long bi = bidx0 + (long)(WIDX) * 64;                                \
    short8 bh0 = bhp[bi], bh1 = bhp[bi + 8192],                               \
           bh2 = bhp[bi + 16384], bh3 = bhp[bi + 24576];                      \
    short8 bl0 = blp[bi], bl1 = blp[bi + 8192],                               \
           bl2 = blp[bi + 16384], bl3 = blp[bi + 24576];                      \
    short8 ah0, al0, ah1, al1;                                                \
    cvt8(&A0[0][0], &ah0, &al0);                                              \
    cvt8(&A0[1][0], &ah1, &al1);                                              \
    A0[0][0] = *reinterpret_cast<const f32x4*>(pA0 + (PREOFF));               \
    A0[0][1] = *reinterpret_cast<const f32x4*>(pA0 + (PREOFF) + 4);           \
    A0[1][0] = *reinterpret_cast<const f32x4*>(pA1 + (PREOFF));               \
    A0[1][1] = *reinterpret_cast<const f32x4*>(pA1 + (PREOFF) + 4);           \
    __builtin_amdgcn_sched_barrier(0);                                        \
    acc[0][0] = __builtin_amdgcn_mfma_f32_16x16x32_bf16(ah0, bh0, acc[0][0], 0, 0, 0); \
    acc[0][0] = __builtin_amdgcn_mfma_f32_16x16x32_bf16(ah0, bl0, acc[0][0], 0, 0, 0); \
    acc[0][0] = __builtin_amdgcn_mfma_f32_16x16x32_bf16(al0, bh0, acc[0][0], 0, 0, 0); \
    acc[0][0] = __builtin_amdgcn_mfma_f32_16x16x32_bf16(al0, bl0, acc[0][0], 0, 0, 0); \
    acc[0][1] = __builtin_amdgcn_mfma_f32_16x16x32_bf16(ah0, bh1, acc[0][1], 0, 0, 0); \
    acc[0][1] = __builtin_amdgcn_mfma_f32_16x16x32_bf16(ah0, bl1, acc[0][1], 0, 0, 0); \
    acc[0][1] = __builtin_amdgcn_mfma_f32_16x16x32_bf16(al0, bh1, acc[0][1], 0, 0, 0); \
    acc[0][1] = __builtin_amdgcn_mfma_f32_16x16x32_bf16(al0, bl1, acc[0][1], 0, 0, 0); \
    acc[0][2] = __builtin_amdgcn_mfma_f32_16x16x32_bf16(ah0, bh2, acc[0][2], 0, 0, 0); \
    acc[0][2] = __builtin_amdgcn_mfma_f32_16x16x32_bf16(ah0, bl2, acc[0][2], 0, 0, 0); \
    acc[0][2] = __builtin_amdgcn_mfma_f32_16x16x32_bf16(al0, bh2, acc[0][2], 0, 0, 0); \
    acc[0][2] = __builtin_amdgcn_mfma_f32_16x16x32_bf16(al0, bl2, acc[0][2], 0, 0, 0); \
    acc[0][3] = __builtin_amdgcn_mfma_f32_16x16x32_bf16(ah0, bh3, acc[0][3], 0, 0, 0); \
    acc[0][3] = __builtin_amdgcn_mfma_f32_16x16x32_bf16(ah0, bl3, acc[0][3], 0, 0, 0); \
    acc[0][3] = __builtin_amdgcn_mfma_f32_16x16x32_bf16(al0, bh3, acc[0][3], 0, 0, 0); \
    acc[0][3] = __builtin_amdgcn_mfma_f32_16x16x32_bf16(al0, bl3, acc[0][3], 0, 0, 0); \
    acc[1][0] = __builtin_amdgcn_mfma_f32_16x16x32_bf16(ah1, bh0, acc[1][0], 0, 0, 0); \
    acc[1][0] = __builtin_amdgcn_mfma_f32_16x16x32_bf16(ah1, bl0, acc[1][0], 0, 0, 0); \
    acc[1][0] = __builtin_amdgcn_mfma_f32_16x16x32_bf16(al1, bh0, acc[1][0], 0, 0, 0); \
    acc[1][0] = __builtin_amdgcn_mfma_f32_16x16x32_bf16(al1, bl0, acc[1][0], 0, 0, 0); \
    acc[1][1] = __builtin_amdgcn_mfma_f32_16x16x32_bf16(ah1, bh1, acc[1][1], 0, 0, 0); \
    acc[1][1] = __builtin_amdgcn_mfma_f32_16x16x32_bf16(ah1, bl1, acc[1][1], 0, 0, 0); \
    acc[1][1] = __builtin_amdgcn_mfma_f32_16x16x32_bf16(al1, bh1, acc[1][1], 0, 0, 0); \
    acc[1][1] = __builtin_amdgcn_mfma_f32_16x16x32_bf16(al1, bl1, acc[1][1], 0, 0, 0); \
    acc[1][2] = __builtin_amdgcn_mfma_f32_16x16x32_bf16(ah1, bh2, acc[1][2], 0, 0, 0); \
    acc[1][2] = __builtin_amdgcn_mfma_f32_16x16x32_bf16(ah1, bl2, acc[1][2], 0, 0, 0); \
    acc[1][2] = __builtin_amdgcn_mfma_f32_16x16x32_bf16(al1, bh2, acc[1][2], 0, 0, 0); \
    acc[1][2] = __builtin_amdgcn_mfma_f32_16x16x32_bf16(al1, bl2, acc[1][2], 0, 0, 0); \
    acc[1][3] = __builtin_amdgcn_mfma_f32_16x16x32_bf16(ah1, bh3, acc[1][3], 0, 0, 0); \
    acc[1][3] = __builtin_amdgcn_mfma_f32_16x16x32_bf16(ah1, bl3, acc[1][3], 0, 0, 0); \
    acc[1][3] = __builtin_amdgcn_mfma_f32_16x16x32_bf16(al1, bh3, acc[1][3], 0, 0, 0); \
    acc[1][3] = __builtin_amdgcn_mfma_f32_16x16x32_bf16(al1, bl3, acc[1][3], 0, 0, 0); \
} while (0)

// Phase 2: streaming partial GEMM. Block = (kc, tt): 32 tokens x 64 experts
// over K-chunk kc; 4 waves K-split the chunk; LDS-reduce the 4 wave
// partials (race-free) and write ONE tile per block to global scratch.
__global__ __launch_bounds__(256, 4)
void gemm_part(const float* __restrict__ x,
               const short8* __restrict__ bhp,
               const short8* __restrict__ blp,
               float* __restrict__ part,
               int M, int K, int nkc, int ttiles) {
    __shared__ float Wp[4][2048];

    const int t  = threadIdx.x;
    const int wv = t >> 6;
    const int ln = t & 63;
    const int fr = ln & 15;
    const int q  = ln >> 4;
    const int tt = blockIdx.x % ttiles;
    const int kc = blockIdx.x / ttiles;
    const long tok0 = (long)tt * 32;

    const int kper    = K / nkc;        // K covered by this block
    const int kwave   = kper >> 2;      // per wave
    const int windows = kwave >> 5;     // k=32 windows per wave
    const int kbase   = kc * kper + wv * kwave + q * 8;
    const int wstart  = (kc * kper + wv * kwave) >> 5;

    const float* pA0 = x + (tok0 + fr) * (long)K + kbase;
    const float* pA1 = x + (tok0 + 16 + fr) * (long)K + kbase;
    const long bidx0 = (long)wstart * 64 + ln;   // + nt*8192 + w*64

    f32x4 acc[2][4];
#pragma unroll
    for (int mt = 0; mt < 2; ++mt)
#pragma unroll
        for (int nt = 0; nt < 4; ++nt) acc[mt][nt] = (f32x4){0.f, 0.f, 0.f, 0.f};

    f32x4 A0[2][2];
    A0[0][0] = *reinterpret_cast<const f32x4*>(pA0);
    A0[0][1] = *reinterpret_cast<const f32x4*>(pA0 + 4);
    A0[1][0] = *reinterpret_cast<const f32x4*>(pA1);
    A0[1][1] = *reinterpret_cast<const f32x4*>(pA1 + 4);

    for (int i = 0; i < windows; ++i) {
        const int pre = (i + 1 < windows) ? (i + 1) * 32 : 0;
        WSTEP(i, pre);
    }

    // per-wave partial -> LDS (C/D layout col=lane&15, row=q*4+r)
    float* myW = &Wp[wv][0];
#pragma unroll
    for (int mt = 0; mt < 2; ++mt)
#pragma unroll
        for (int nt = 0; nt < 4; ++nt)
#pragma unroll
            for (int r = 0; r < 4; ++r)
                myW[(mt * 16 + q * 4 + r) * 64 + nt * 16 + fr] = acc[mt][nt][r];
    __syncthreads();

    // block-reduce 4 wave partials, single coalesced global write
    float* pt = part + ((long)kc * ttiles + tt) * 2048;
    for (int idx = t; idx < 2048; idx += 256)
        pt[idx] = (Wp[0][idx] + Wp[1][idx]) + (Wp[2][idx] + Wp[3][idx]);
}

// Phase 3: reduce partials, top-2 + softmax-of-top-2, fp64 refine near-ties.
__global__ __launch_bounds__(256, 2)
void reduce_topk(const float* __restrict__ part,
                 const float* __restrict__ x,
                 const float* __restrict__ gw,
                 float* __restrict__ out,
                 int M, int K, int nkc, int ttiles) {
    __shared__ float Ls[64 * LROW];
    __shared__ int flags[64];
    __shared__ double Ld4[4][64];

    const int t  = threadIdx.x;
    const int wv = t >> 6;
    const int ln = t & 63;
    const long g0 = (long)blockIdx.x * 64;

    for (int idx = t; idx < 4096; idx += 256) {
        const int tok = idx >> 6, e = idx & 63;
        const int tt  = (int)(g0 >> 5) + (tok >> 5);
        const int rr  = tok & 31;
        float s = 0.f;
        for (int kc = 0; kc < nkc; ++kc)
            s += part[((long)kc * ttiles + tt) * 2048 + rr * 64 + e];
        Ls[tok * LROW + e] = s;
    }
    __syncthreads();

    if (t < 64) {
        const float* row = Ls + (long)t * LROW;
        float m1 = -INFINITY, m2 = -INFINITY, m3 = -INFINITY;
        int i1 = 0, i2 = 0;
#pragma unroll 8
        for (int e = 0; e < 64; ++e) {
            const float v = row[e];
            if (v > m1)      { m3 = m2; m2 = m1; i2 = i1; m1 = v; i1 = e; }
            else if (v > m2) { m3 = m2; m2 = v; i2 = e; }
            else if (v > m3) { m3 = v; }
        }
        const float e2 = expf(m2 - m1);
        const float s  = 1.0f + e2;

        const long g = g0 + t;
        out[2 * g + 0] = 1.0f / s;
        out[2 * g + 1] = e2 / s;
        float* oi = out + 2 * (long)M;
        oi[2 * g + 0] = (float)i1;
        oi[2 * g + 1] = (float)i2;

        flags[t] = ((m1 - m2) < TAU) | ((m2 - m3) < TAU);
    }
    __syncthreads();

    for (int tk = 0; tk < 64; ++tk) {
        if (flags[tk]) {
            const float* xr = x + (g0 + tk) * (long)K + wv * 1024;
            const float* gr = gw + (long)ln * (long)K + wv * 1024;
            double s0 = 0.0, s1 = 0.0, s2 = 0.0, s3 = 0.0;
            for (int k = 0; k < 1024; k += 4) {
                const f32x4 a = *reinterpret_cast<const f32x4*>(xr + k);
                const f32x4 b = *reinterpret_cast<const f32x4*>(gr + k);
                s0 = fma((double)a.x, (double)b.x, s0);
                s1 = fma((double)a.y, (double)b.y, s1);
                s2 = fma((double)a.z, (double)b.z, s2);
                s3 = fma((double)a.w, (double)b.w, s3);
            }
            Ld4[wv][ln] = (s0 + s1) + (s2 + s3);
            __syncthreads();
            if (t == 0) {
                double m1 = -INFINITY, m2 = -INFINITY;
                int i1 = 0, i2 = 0;
                for (int e = 0; e < 64; ++e) {
                    const double v = Ld4[0][e] + Ld4[1][e] + Ld4[2][e] + Ld4[3][e];
                    if (v > m1)      { m2 = m1; i2 = i1; m1 = v; i1 = e; }
                    else if (v > m2) { m2 = v; i2 = e; }
                }
                const double e2 = exp(m2 - m1);
                const double s  = 1.0 + e2;
                const long g = g0 + tk;
                out[2 * g + 0] = (float)(1.0 / s);
                out[2 * g + 1] = (float)(e2 / s);
                float* oi = out + 2 * (long)M;
                oi[2 * g + 0] = (float)i1;
                oi[2 * g + 1] = (float)i2;
            }
            __syncthreads();
        }
    }
}

// Fallback (ws too small for partials): R8-equivalent single kernel.
__global__ __launch_bounds__(256, 4)
void router_single(const float* __restrict__ x,
                   const short8* __restrict__ bhp,
                   const short8* __restrict__ blp,
                   const float* __restrict__ gw,
                   float* __restrict__ out,
                   int M, int K) {
    __shared__ float Lp[4 * 32 * LROW];
    __shared__ int flags[32];
    __shared__ double Ld4[4][64];

    const int t  = threadIdx.x;
    const int wv = t >> 6;
    const int ln = t & 63;
    const int fr = ln & 15;
    const int q  = ln >> 4;
    const long tok0 = (long)blockIdx.x * 32;

    const int kbase = wv * 1024 + q * 8;
    const float* pA0 = x + (tok0 + fr) * (long)K + kbase;
    const float* pA1 = x + (tok0 + 16 + fr) * (long)K + kbase;
    const long bidx0 = (long)(wv * 32) * 64 + ln;

    f32x4 acc[2][4];
#pragma unroll
    for (int mt = 0; mt < 2; ++mt)
#pragma unroll
        for (int nt = 0; nt < 4; ++nt) acc[mt][nt] = (f32x4){0.f, 0.f, 0.f, 0.f};

    f32x4 A0[2][2];
    A0[0][0] = *reinterpret_cast<const f32x4*>(pA0);
    A0[0][1] = *reinterpret_cast<const f32x4*>(pA0 + 4);
    A0[1][0] = *reinterpret_cast<const f32x4*>(pA1);
    A0[1][1] = *reinterpret_cast<const f32x4*>(pA1 + 4);

    for (int i = 0; i < 32; ++i) {
        const int pre = (i + 1 < 32) ? (i + 1) * 32 : 0;
        WSTEP(i, pre);
    }

    float* myLp = Lp + wv * (32 * LROW);
#pragma unroll
    for (int mt = 0; mt < 2; ++mt)
#pragma unroll
        for (int nt = 0; nt < 4; ++nt)
#pragma unroll
            for (int r = 0; r < 4; ++r)
                myLp[(mt * 16 + q * 4 + r) * LROW + nt * 16 + fr] = acc[mt][nt][r];
    __syncthreads();

    for (int i = t; i < 32 * LROW; i += 256)
        Lp[i] = (Lp[i] + Lp[32 * LROW + i])
              + (Lp[2 * 32 * LROW + i] + Lp[3 * 32 * LROW + i]);
    __syncthreads();

    if (t < 32) {
        const float* row = Lp + (long)t * LROW;
        float m1 = -INFINITY, m2 = -INFINITY, m3 = -INFINITY;
        int i1 = 0, i2 = 0;
#pragma unroll 8
        for (int e = 0; e < 64; ++e) {
            const float v = row[e];
            if (v > m1)      { m3 = m2; m2 = m1; i2 = i1; m1 = v; i1 = e; }
            else if (v > m2) { m3 = m2; m2 = v; i2 = e; }
            else if (v > m3) { m3 = v; }
        }
        const float e2 = expf(m2 - m1);
        const float s  = 1.0f + e2;
        const long g = tok0 + t;
        out[2 * g + 0] = 1.0f / s;
        out[2 * g + 1] = e2 / s;
        float* oi = out + 2 * (long)M;
        oi[2 * g + 0] = (float)i1;
        oi[2 * g + 1] = (float)i2;
        flags[t] = ((m1 - m2) < TAU) | ((m2 - m3) < TAU);
    }
    __syncthreads();

    for (int tk = 0; tk < 32; ++tk) {
        if (flags[tk]) {
            const float* xr = x + (tok0 + tk) * (long)K + wv * 1024;
            const float* gr = gw + (long)ln * (long)K + wv * 1024;
            double s0 = 0.0, s1 = 0.0, s2 = 0.0, s3 = 0.0;
            for (int k = 0; k < 1024; k += 4) {
                const f32x4 a = *reinterpret_cast<const f32x4*>(xr + k);
                const f32x4 b = *reinterpret_cast<const f32x4*>(gr + k);
                s0 = fma((double)a.x, (double)b.x, s0);
                s1 = fma((double)a.y, (double)b.y, s1);
                s2 = fma((double)a.z, (double)b.z, s2);
                s3 = fma((double)a.w, (double)b.w, s3);
            }
            Ld4[wv][ln] = (s0 + s1) + (s2 + s3);
            __syncthreads();
            if (t == 0) {
                double m1 = -INFINITY, m2 = -INFINITY;
                int i1 = 0, i2 = 0;
                for (int e = 0; e < 64; ++e) {
                    const double v = Ld4[0][e] + Ld4[1][e] + Ld4[2][e] + Ld4[3][e];
                    if (v > m1)      { m2 = m1; i2 = i1; m1 = v; i1 = e; }
                    else if (v > m2) { m2 = v; i2 = e; }
                }
                const double e2 = exp(m2 - m1);
                const double s  = 1.0 + e2;
                const long g = tok0 + tk;
                out[2 * g + 0] = (float)(1.0 / s);
                out[2 * g + 1] = (float)(e2 / s);
                float* oi = out + 2 * (long)M;
                oi[2 * g + 0] = (float)i1;
                oi[2 * g + 1] = (float)i2;
            }
            __syncthreads();
        }
    }
}

extern "C" void kernel_launch(void* const* d_in, const int* in_sizes, int n_in,
                              void* d_out, int out_size, void* d_ws, size_t ws_size,
                              hipStream_t stream) {
    const float* x  = (const float*)d_in[0];
    const float* gw = (const float*)d_in[1];
    float* out = (float*)d_out;

    const int K = 4096;
    const int M = in_sizes[0] / K;          // 32768 tokens
    const int ttiles = M / 32;              // 1024

    const size_t bbytes = 2ull * 32768 * sizeof(short8);   // 1 MB packed B
    const size_t per_kc = (size_t)M * 64 * sizeof(float);  // 8 MB partials

    short8* bh = (short8*)d_ws;
    short8* bl = bh + 32768;
    float* part = (float*)(bl + 32768);

    int nkc = 0;
    if (ws_size >= bbytes + 4 * per_kc)      nkc = 4;
    else if (ws_size >= bbytes + 2 * per_kc) nkc = 2;
    else if (ws_size >= bbytes + 1 * per_kc) nkc = 1;

    prep_b<<<128, 256, 0, stream>>>(gw, bh, bl);
    if (nkc > 0) {
        gemm_part<<<nkc * ttiles, 256, 0, stream>>>(x, bh, bl, part, M, K, nkc, ttiles);
        reduce_topk<<<M / 64, 256, 0, stream>>>(part, x, gw, out, M, K, nkc, ttiles);
    } else {
        router_single<<<ttiles, 256, 0, stream>>>(x, bh, bl, gw, out, M, K);
    }
}

// Round 13
// 242.852 us; speedup vs baseline: 1.1973x; 1.1973x over previous
//
#include <hip/hip_runtime.h>
#include <hip/hip_bf16.h>
#include <math.h>

// TopK router: logits = x @ gate_w^T, softmax, top-2, renormalize.
// M=32768 tokens, K=4096, E=64 experts.
// Outputs (concat, harness reads whole buffer as float32):
//   d_out[0 .. 2M)  : top-2 weights (descending)
//   d_out[2M .. 4M) : top-2 expert indices, stored as float values
//
// R13: async global_load_lds streaming (the R4-R9 family was Little's-law
// bound: VGPR load-dests capped in-flight bytes at ~3KB/CU -> ~800 GB/s).
// DMA loads have no VGPR destination -> deep queues. Per 64-token block:
// 64 chunks of k=64; stage A(16KB f32, source-swizzled) + packed-B slice
// (16KB bf16 hi/lo) into double-buffered LDS; 1 barrier/chunk; each wave
// owns 1 m-tile x 4 n-tiles and accumulates the FULL K (no reduce).
// A-tile LDS: linear dest (DMA requirement), bank conflicts killed by
// pre-swizzling the per-lane GLOBAL slot (j ^ (row&15)) and XOR-ing the
// same key on ds_read (m173 pattern). Epilogue: proven top-3 + TAU +
// parallel fp64 refine.

typedef __attribute__((ext_vector_type(8))) short short8;
typedef __attribute__((ext_vector_type(4))) float f32x4;

#define TAU 1e-4f   // near-tie refine threshold (4-term logit noise ~1e-6)
#define LROW 68     // padded logits stride (floats)

__device__ __forceinline__ void cvt8(const f32x4* v, short8* hi, short8* lo) {
    const float* f = reinterpret_cast<const float*>(v);
#pragma unroll
    for (int j = 0; j < 8; ++j) {
        __hip_bfloat16 h = __float2bfloat16(f[j]);
        float r = f[j] - __bfloat162float(h);
        __hip_bfloat16 l = __float2bfloat16(r);
        (*hi)[j] = (short)*reinterpret_cast<unsigned short*>(&h);
        (*lo)[j] = (short)*reinterpret_cast<unsigned short*>(&l);
    }
}

// Pack gw (64x4096 f32) into MFMA-fragment-ordered bf16 hi/lo arrays:
// entry (nt*8192 + w*64 + ln) holds 8 bf16 of row nt*16+(ln&15),
// k = w*32 + (ln>>4)*8 .. +8.
__global__ void prep_b(const float* __restrict__ gw,
                       short8* __restrict__ bh, short8* __restrict__ bl) {
    const int tid = blockIdx.x * 256 + threadIdx.x;   // 0..32767
    const int ln  = tid & 63;
    const int w   = (tid >> 6) & 127;
    const int nt  = tid >> 13;
    const int row = nt * 16 + (ln & 15);
    const int k   = w * 32 + ((ln >> 4) << 3);
    f32x4 v[2];
    v[0] = *reinterpret_cast<const f32x4*>(gw + (long)row * 4096 + k);
    v[1] = *reinterpret_cast<const f32x4*>(gw + (long)row * 4096 + k + 4);
    short8 h, l;
    cvt8(v, &h, &l);
    bh[tid] = h;
    bl[tid] = l;
}

__device__ __forceinline__ void gload16(const void* g, void* l) {
    __builtin_amdgcn_global_load_lds(
        (const __attribute__((address_space(1))) void*)g,
        (__attribute__((address_space(3))) void*)l, 16, 0, 0);
}

// LDS map (char AB[65536]):
//   A buf0 @0, A buf1 @16384       : [64 rows][256 B] (slot-swizzled content)
//   B buf0 @32768, B buf1 @49152   : 16 segs of 1KB: seg=((w*4+nt)*2+hl)
#define STAGE(C, BUF) do {                                                    \
    char* aB = &AB[(BUF) * 16384];                                            \
    char* bB = &AB[32768 + (BUF) * 16384];                                    \
    _Pragma("unroll")                                                         \
    for (int i = 0; i < 4; ++i)                                               \
        gload16(srcA[i] + (C) * 256, aB + (wv * 16 + i * 4) * 256);           \
    _Pragma("unroll")                                                         \
    for (int i = 0; i < 4; ++i) {                                             \
        const int seg = wv * 4 + i;                                           \
        const short8* sp = ((seg & 1) ? blp : bhp)                            \
            + (((seg >> 1) & 3) * 8192 + (2 * (C) + (seg >> 3)) * 64 + ln);   \
        gload16(sp, bB + seg * 1024);                                         \
    }                                                                         \
} while (0)

#define COMPUTE(BUF) do {                                                     \
    const char* aB = &AB[(BUF) * 16384];                                      \
    const char* bB = &AB[32768 + (BUF) * 16384];                              \
    _Pragma("unroll")                                                         \
    for (int w = 0; w < 2; ++w) {                                             \
        f32x4 av[2];                                                          \
        const int rbase = (wv * 16 + fr) * 256;                               \
        av[0] = *(const f32x4*)(aB + rbase + (((w * 8 + q * 2 + 0) ^ fr) * 16)); \
        av[1] = *(const f32x4*)(aB + rbase + (((w * 8 + q * 2 + 1) ^ fr) * 16)); \
        short8 ah, al;                                                        \
        cvt8(av, &ah, &al);                                                   \
        _Pragma("unroll")                                                     \
        for (int nt = 0; nt < 4; ++nt) {                                      \
            short8 bh = *(const short8*)(bB + ((w * 4 + nt) * 2 + 0) * 1024 + ln * 16); \
            short8 bl = *(const short8*)(bB + ((w * 4 + nt) * 2 + 1) * 1024 + ln * 16); \
            acc[nt] = __builtin_amdgcn_mfma_f32_16x16x32_bf16(ah, bh, acc[nt], 0, 0, 0); \
            acc[nt] = __builtin_amdgcn_mfma_f32_16x16x32_bf16(ah, bl, acc[nt], 0, 0, 0); \
            acc[nt] = __builtin_amdgcn_mfma_f32_16x16x32_bf16(al, bh, acc[nt], 0, 0, 0); \
            acc[nt] = __builtin_amdgcn_mfma_f32_16x16x32_bf16(al, bl, acc[nt], 0, 0, 0); \
        }                                                                     \
    }                                                                         \
} while (0)

__global__ __launch_bounds__(256, 2)
void router_fused(const float* __restrict__ x,
                  const short8* __restrict__ bhp,
                  const short8* __restrict__ blp,
                  const float* __restrict__ gw,
                  float* __restrict__ out,
                  int M, int K) {
    __shared__ __align__(16) char AB[65536];
    __shared__ int flags[64];
    __shared__ double Ld4[4][64];

    const int t  = threadIdx.x;
    const int wv = t >> 6;
    const int ln = t & 63;
    const int fr = ln & 15;
    const int q  = ln >> 4;
    const long tok0 = (long)blockIdx.x * 64;

    // Per-lane A staging sources. Staging instr i of wave wv covers rows
    // wv*16+i*4 .. +4; lane ln -> row (+ln>>4), slot (ln&15). Global slot is
    // pre-swizzled by (row&15) = (i*4 + q), inverted on the read side.
    const char* srcA[4];
#pragma unroll
    for (int i = 0; i < 4; ++i) {
        const int row  = wv * 16 + i * 4 + q;
        const int slot = (ln & 15) ^ (i * 4 + q);
        srcA[i] = (const char*)x + ((tok0 + row) * (long)K) * 4 + slot * 16;
    }

    f32x4 acc[4];
#pragma unroll
    for (int nt = 0; nt < 4; ++nt) acc[nt] = (f32x4){0.f, 0.f, 0.f, 0.f};

    STAGE(0, 0);
    __syncthreads();            // drain vmcnt(0): buf0 ready
    STAGE(1, 1);

    for (int c = 0; c < 64; ++c) {
        const int buf = c & 1;
        COMPUTE(buf);
        __syncthreads();        // all read buf; drains stage(c+1) loads
        if (c + 2 < 64) STAGE(c + 2, buf);
    }

    // ---- epilogue: dump logits (C/D: col=lane&15, row=q*4+r) ----
    float* Ls = (float*)AB;     // 64*68*4 = 17.4 KB, aliases A buffers
#pragma unroll
    for (int nt = 0; nt < 4; ++nt)
#pragma unroll
        for (int r = 0; r < 4; ++r)
            Ls[(wv * 16 + q * 4 + r) * LROW + nt * 16 + fr] = acc[nt][r];
    __syncthreads();

    if (t < 64) {
        const float* row = Ls + (long)t * LROW;
        float m1 = -INFINITY, m2 = -INFINITY, m3 = -INFINITY;
        int i1 = 0, i2 = 0;
#pragma unroll 8
        for (int e = 0; e < 64; ++e) {
            const float v = row[e];
            if (v > m1)      { m3 = m2; m2 = m1; i2 = i1; m1 = v; i1 = e; }
            else if (v > m2) { m3 = m2; m2 = v; i2 = e; }
            else if (v > m3) { m3 = v; }
        }
        const float e2 = expf(m2 - m1);
        const float s  = 1.0f + e2;

        const long g = tok0 + t;
        out[2 * g + 0] = 1.0f / s;
        out[2 * g + 1] = e2 / s;
        float* oi = out + 2 * (long)M;
        oi[2 * g + 0] = (float)i1;
        oi[2 * g + 1] = (float)i2;

        flags[t] = ((m1 - m2) < TAU) | ((m2 - m3) < TAU);
    }
    __syncthreads();

    // ---- fp64 refine, 256 threads cooperate (wave=K-quarter, lane=expert) ----
    for (int tk = 0; tk < 64; ++tk) {
        if (flags[tk]) {
            const float* xr = x + (tok0 + tk) * (long)K + wv * 1024;
            const float* gr = gw + (long)ln * (long)K + wv * 1024;
            double s0 = 0.0, s1 = 0.0, s2 = 0.0, s3 = 0.0;
            for (int k = 0; k < 1024; k += 4) {
                const f32x4 a = *reinterpret_cast<const f32x4*>(xr + k);
                const f32x4 b = *reinterpret_cast<const f32x4*>(gr + k);
                s0 = fma((double)a.x, (double)b.x, s0);
                s1 = fma((double)a.y, (double)b.y, s1);
                s2 = fma((double)a.z, (double)b.z, s2);
                s3 = fma((double)a.w, (double)b.w, s3);
            }
            Ld4[wv][ln] = (s0 + s1) + (s2 + s3);
            __syncthreads();
            if (t == 0) {
                double m1 = -INFINITY, m2 = -INFINITY;
                int i1 = 0, i2 = 0;
                for (int e = 0; e < 64; ++e) {
                    const double v = Ld4[0][e] + Ld4[1][e] + Ld4[2][e] + Ld4[3][e];
                    if (v > m1)      { m2 = m1; i2 = i1; m1 = v; i1 = e; }
                    else if (v > m2) { m2 = v; i2 = e; }
                }
                const double e2 = exp(m2 - m1);
                const double s  = 1.0 + e2;
                const long g = tok0 + tk;
                out[2 * g + 0] = (float)(1.0 / s);
                out[2 * g + 1] = (float)(e2 / s);
                float* oi = out + 2 * (long)M;
                oi[2 * g + 0] = (float)i1;
                oi[2 * g + 1] = (float)i2;
            }
            __syncthreads();
        }
    }
}

extern "C" void kernel_launch(void* const* d_in, const int* in_sizes, int n_in,
                              void* d_out, int out_size, void* d_ws, size_t ws_size,
                              hipStream_t stream) {
    const float* x  = (const float*)d_in[0];
    const float* gw = (const float*)d_in[1];
    float* out = (float*)d_out;

    const int K = 4096;
    const int M = in_sizes[0] / K;          // 32768 tokens
    const int nblocks = M / 64;             // 512

    short8* bh = (short8*)d_ws;             // 1 MB total, proven to fit
    short8* bl = bh + 32768;

    prep_b<<<128, 256, 0, stream>>>(gw, bh, bl);
    router_fused<<<nblocks, 256, 0, stream>>>(x, bh, bl, gw, out, M, K);
}

// Round 14
// 236.299 us; speedup vs baseline: 1.2305x; 1.0277x over previous
//
#include <hip/hip_runtime.h>
#include <hip/hip_bf16.h>
#include <math.h>

// TopK router: logits = x @ gate_w^T, softmax, top-2, renormalize.
// M=32768 tokens, K=4096, E=64 experts.
// Outputs (concat, harness reads whole buffer as float32):
//   d_out[0 .. 2M)  : top-2 weights (descending)
//   d_out[2M .. 4M) : top-2 expert indices, stored as float values
//
// R14 = R13's DMA streaming + T3/T4 counted vmcnt (NEVER drain to 0 in the
// loop; R13's __syncthreads drained every chunk -> 1 chunk in flight ->
// 2.2 TB/s). 32 tokens/block x 1024 blocks (4 blocks/CU). Chunk k=32:
// A 4KB (source-swizzled, linear DMA dest) + B 8KB (prep_b packed bf16
// hi/lo). Per wave per chunk: 3 DMA instr. Loop: vmcnt(3) -> s_barrier ->
// compute (wave = 16 tok x 32 exp, full K, 8 MFMA 4-term) -> s_barrier ->
// STAGE(c+2). Epilogue: proven top-3 + TAU=1e-4 + parallel fp64 refine.

typedef __attribute__((ext_vector_type(8))) short short8;
typedef __attribute__((ext_vector_type(4))) float f32x4;

#define TPB 32
#define NCH 128     // K/32 chunks
#define TAU 1e-4f
#define LROW 68

__device__ __forceinline__ void cvt8(const f32x4* v, short8* hi, short8* lo) {
    const float* f = reinterpret_cast<const float*>(v);
#pragma unroll
    for (int j = 0; j < 8; ++j) {
        __hip_bfloat16 h = __float2bfloat16(f[j]);
        float r = f[j] - __bfloat162float(h);
        __hip_bfloat16 l = __float2bfloat16(r);
        (*hi)[j] = (short)*reinterpret_cast<unsigned short*>(&h);
        (*lo)[j] = (short)*reinterpret_cast<unsigned short*>(&l);
    }
}

// Pack gw into MFMA-fragment order: entry (nt*8192 + w*64 + ln) = 8 bf16 of
// row nt*16+(ln&15), k = w*32 + (ln>>4)*8.
__global__ void prep_b(const float* __restrict__ gw,
                       short8* __restrict__ bh, short8* __restrict__ bl) {
    const int tid = blockIdx.x * 256 + threadIdx.x;
    const int ln  = tid & 63;
    const int w   = (tid >> 6) & 127;
    const int nt  = tid >> 13;
    const int row = nt * 16 + (ln & 15);
    const int k   = w * 32 + ((ln >> 4) << 3);
    f32x4 v[2];
    v[0] = *reinterpret_cast<const f32x4*>(gw + (long)row * 4096 + k);
    v[1] = *reinterpret_cast<const f32x4*>(gw + (long)row * 4096 + k + 4);
    short8 h, l;
    cvt8(v, &h, &l);
    bh[tid] = h;
    bl[tid] = l;
}

__device__ __forceinline__ void gload16(const void* g, void* l) {
    __builtin_amdgcn_global_load_lds(
        (const __attribute__((address_space(1))) void*)g,
        (__attribute__((address_space(3))) void*)l, 16, 0, 0);
}

// LDS: A0 @0 (4KB), A1 @4096, B0 @8192 (8KB), B1 @16384. Total 24KB.
#define STAGE(C, BUF) do {                                                    \
    char* aB = AB + (BUF) * 4096;                                             \
    char* bB = AB + 8192 + (BUF) * 8192;                                      \
    gload16(srcA + (long)(C) * 128, aB + wv * 1024 + ln * 16);                \
    gload16(bhp + (long)wv * 8192 + (C) * 64 + ln, bB + (wv * 2 + 0) * 1024 + ln * 16); \
    gload16(blp + (long)wv * 8192 + (C) * 64 + ln, bB + (wv * 2 + 1) * 1024 + ln * 16); \
} while (0)

__global__ __launch_bounds__(256, 4)
void router_fused(const float* __restrict__ x,
                  const short8* __restrict__ bhp,
                  const short8* __restrict__ blp,
                  const float* __restrict__ gw,
                  float* __restrict__ out,
                  int M, int K) {
    __shared__ __align__(16) char AB[24576];
    __shared__ int flags[TPB];
    __shared__ double Ld4[4][64];

    const int t  = threadIdx.x;
    const int wv = t >> 6;
    const int ln = t & 63;
    const int fr = ln & 15;
    const int q  = ln >> 4;
    const int mm = wv >> 1;                 // m-tile (16 tokens)
    const int nn = wv & 1;                  // n-half (32 experts)
    const long tok0 = (long)blockIdx.x * TPB;

    // A staging source: lane stages local row wv*8+(ln>>3), preswizzled slot
    const int arow = wv * 8 + (ln >> 3);
    const int sw   = (ln & 7) ^ (ln >> 3);
    const char* srcA = (const char*)(x + (tok0 + arow) * (long)K) + sw * 16;

    f32x4 acc[2];
    acc[0] = (f32x4){0.f, 0.f, 0.f, 0.f};
    acc[1] = (f32x4){0.f, 0.f, 0.f, 0.f};

    STAGE(0, 0);
    STAGE(1, 1);

    for (int c = 0; c < NCH; ++c) {
        const int buf = c & 1;
        if (c + 1 < NCH) asm volatile("s_waitcnt vmcnt(3)" ::: "memory");
        else             asm volatile("s_waitcnt vmcnt(0)" ::: "memory");
        __builtin_amdgcn_s_barrier();
        asm volatile("" ::: "memory");
        __builtin_amdgcn_sched_barrier(0);

        // ---- compute chunk c from buf ----
        {
            const char* aB = AB + buf * 4096;
            const char* bB = AB + 8192 + buf * 8192;
            const int r = mm * 16 + fr;
            f32x4 av[2];
            av[0] = *(const f32x4*)(aB + r * 128 + (((q * 2 + 0) ^ (fr & 7)) * 16));
            av[1] = *(const f32x4*)(aB + r * 128 + (((q * 2 + 1) ^ (fr & 7)) * 16));
            short8 ah, al;
            cvt8(av, &ah, &al);
#pragma unroll
            for (int ntl = 0; ntl < 2; ++ntl) {
                const int nt = 2 * nn + ntl;
                short8 bhv = *(const short8*)(bB + (nt * 2 + 0) * 1024 + ln * 16);
                short8 blv = *(const short8*)(bB + (nt * 2 + 1) * 1024 + ln * 16);
                acc[ntl] = __builtin_amdgcn_mfma_f32_16x16x32_bf16(ah, bhv, acc[ntl], 0, 0, 0);
                acc[ntl] = __builtin_amdgcn_mfma_f32_16x16x32_bf16(ah, blv, acc[ntl], 0, 0, 0);
                acc[ntl] = __builtin_amdgcn_mfma_f32_16x16x32_bf16(al, bhv, acc[ntl], 0, 0, 0);
                acc[ntl] = __builtin_amdgcn_mfma_f32_16x16x32_bf16(al, blv, acc[ntl], 0, 0, 0);
            }
        }

        __builtin_amdgcn_sched_barrier(0);
        asm volatile("" ::: "memory");
        __builtin_amdgcn_s_barrier();       // all waves done reading buf
        asm volatile("" ::: "memory");
        if (c + 2 < NCH) STAGE(c + 2, buf);
        __builtin_amdgcn_sched_barrier(0);
    }

    // ---- epilogue: dump logits (C/D: col=lane&15, row=q*4+r) ----
    __syncthreads();
    float* Ls = (float*)AB;                 // 32*68*4 = 8.7KB, loop is done
#pragma unroll
    for (int ntl = 0; ntl < 2; ++ntl)
#pragma unroll
        for (int r = 0; r < 4; ++r)
            Ls[(mm * 16 + q * 4 + r) * LROW + (2 * nn + ntl) * 16 + fr] = acc[ntl][r];
    __syncthreads();

    if (t < TPB) {
        const float* row = Ls + (long)t * LROW;
        float m1 = -INFINITY, m2 = -INFINITY, m3 = -INFINITY;
        int i1 = 0, i2 = 0;
#pragma unroll 8
        for (int e = 0; e < 64; ++e) {
            const float v = row[e];
            if (v > m1)      { m3 = m2; m2 = m1; i2 = i1; m1 = v; i1 = e; }
            else if (v > m2) { m3 = m2; m2 = v; i2 = e; }
            else if (v > m3) { m3 = v; }
        }
        const float e2 = expf(m2 - m1);
        const float s  = 1.0f + e2;

        const long g = tok0 + t;
        out[2 * g + 0] = 1.0f / s;
        out[2 * g + 1] = e2 / s;
        float* oi = out + 2 * (long)M;
        oi[2 * g + 0] = (float)i1;
        oi[2 * g + 1] = (float)i2;

        flags[t] = ((m1 - m2) < TAU) | ((m2 - m3) < TAU);
    }
    __syncthreads();

    // ---- fp64 refine, 256 threads cooperate (wave=K-quarter, lane=expert) ----
    for (int tk = 0; tk < TPB; ++tk) {
        if (flags[tk]) {
            const float* xr = x + (tok0 + tk) * (long)K + wv * 1024;
            const float* gr = gw + (long)ln * (long)K + wv * 1024;
            double s0 = 0.0, s1 = 0.0, s2 = 0.0, s3 = 0.0;
            for (int k = 0; k < 1024; k += 4) {
                const f32x4 a = *reinterpret_cast<const f32x4*>(xr + k);
                const f32x4 b = *reinterpret_cast<const f32x4*>(gr + k);
                s0 = fma((double)a.x, (double)b.x, s0);
                s1 = fma((double)a.y, (double)b.y, s1);
                s2 = fma((double)a.z, (double)b.z, s2);
                s3 = fma((double)a.w, (double)b.w, s3);
            }
            Ld4[wv][ln] = (s0 + s1) + (s2 + s3);
            __syncthreads();
            if (t == 0) {
                double m1 = -INFINITY, m2 = -INFINITY;
                int i1 = 0, i2 = 0;
                for (int e = 0; e < 64; ++e) {
                    const double v = Ld4[0][e] + Ld4[1][e] + Ld4[2][e] + Ld4[3][e];
                    if (v > m1)      { m2 = m1; i2 = i1; m1 = v; i1 = e; }
                    else if (v > m2) { m2 = v; i2 = e; }
                }
                const double e2 = exp(m2 - m1);
                const double s  = 1.0 + e2;
                const long g = tok0 + tk;
                out[2 * g + 0] = (float)(1.0 / s);
                out[2 * g + 1] = (float)(e2 / s);
                float* oi = out + 2 * (long)M;
                oi[2 * g + 0] = (float)i1;
                oi[2 * g + 1] = (float)i2;
            }
            __syncthreads();
        }
    }
}

extern "C" void kernel_launch(void* const* d_in, const int* in_sizes, int n_in,
                              void* d_out, int out_size, void* d_ws, size_t ws_size,
                              hipStream_t stream) {
    const float* x  = (const float*)d_in[0];
    const float* gw = (const float*)d_in[1];
    float* out = (float*)d_out;

    const int K = 4096;
    const int M = in_sizes[0] / K;          // 32768 tokens
    const int nblocks = M / TPB;            // 1024

    short8* bh = (short8*)d_ws;             // 1 MB packed B
    short8* bl = bh + 32768;

    prep_b<<<128, 256, 0, stream>>>(gw, bh, bl);
    router_fused<<<nblocks, 256, 0, stream>>>(x, bh, bl, gw, out, M, K);
}